// Round 1
// baseline (408.387 us; speedup 1.0000x reference)
//
#include <hip/hip_runtime.h>
#include <math.h>

#define NA 16
#define NBEAM 12
#define NUSER 8

// ws layout: [0 .. 1535]  : steering table, 12 beams x (16 cos | 16 sin) floats
//            [1536..1543] : double accumulator
//            [1544..1547] : done-block counter (finalize fusion)
#define ACC_OFFSET 1536

__global__ void mtl_angles_kernel(const float* __restrict__ Hc_r, const float* __restrict__ Hc_i,
                                  const float* __restrict__ Hs_r, const float* __restrict__ Hs_i,
                                  float* __restrict__ table, double* __restrict__ acc,
                                  unsigned* __restrict__ done) {
    int t = threadIdx.x;
    if (t == 0) { *acc = 0.0; *done = 0u; }   // ws is poisoned 0xAA each iteration
    if (t >= NBEAM) return;

    const float* re;
    const float* im;
    if (t < NUSER) { re = Hc_r + t * NA;           im = Hc_i + t * NA; }          // Hc[0, t, :]
    else           { re = Hs_r + (t - NUSER) * NA; im = Hs_i + (t - NUSER) * NA; } // Hs[0, t, :]

    const float PI_F   = 3.14159265358979323846f;
    const float TWO_PI = 6.28318530717958647692f;

    float ph[NA];
    #pragma unroll
    for (int n = 0; n < NA; ++n) ph[n] = atan2f(im[n], re[n]);

    // unwrapped[0]=0; unwrapped[n]=cumsum of wrapped diffs. n_c = n - 7.5, sum(n_c^2)=340.
    float unw = 0.f, dotsum = 0.f;
    #pragma unroll
    for (int n = 1; n < NA; ++n) {
        float pd = ph[n] - ph[n - 1];
        float x  = pd + PI_F;
        float m  = fmodf(x, TWO_PI);       // python % has sign of divisor
        if (m < 0.f) m += TWO_PI;
        pd = m - PI_F;
        unw += pd;
        dotsum += unw * ((float)n - 7.5f);
    }
    float slope = dotsum / 340.0f;
    float sin_theta = slope / PI_F;        // slope * WAVELENGTH / (2*pi*D), D=0.5, lambda=1
    sin_theta = fminf(1.0f, fmaxf(-1.0f, sin_theta));
    // angle = -asin(sin_theta); steering uses sin(angle) = -sin_theta
    float st = -sin_theta;

    #pragma unroll
    for (int n = 0; n < NA; ++n) {
        float phase = PI_F * st * (float)n;    // 2*pi*D*st*n/lambda = pi*st*n
        table[t * 2 * NA + n]      = cosf(phase);
        table[t * 2 * NA + NA + n] = sinf(phase);
    }
}

__device__ __forceinline__ float dot4(float4 a, float4 b) {
    return a.x * b.x + a.y * b.y + a.z * b.z + a.w * b.w;
}

// Async global->LDS, 16 B per lane. LDS dest is wave-uniform base + lane*16.
__device__ __forceinline__ void load_lds16(const float* g, float* l) {
    __builtin_amdgcn_global_load_lds(
        (const __attribute__((address_space(1))) void*)g,
        (__attribute__((address_space(3))) void*)l, 16, 0, 0);
}

// Full-row loss (all 12 beams) — used only by the generic tail path.
__device__ __forceinline__ float row_loss(const float4* w, const float* tbs) {
    float minU = 3.4e38f, sumU = 0.f, sumT = 0.f;
    #pragma unroll 1
    for (int j = 0; j < NBEAM; ++j) {
        const float4* tc = (const float4*)(tbs + j * 32);
        float re = 0.f, im = 0.f;
        #pragma unroll
        for (int q = 0; q < 4; ++q) {
            float4 c = tc[q], s = tc[q + 4];
            float4 wr = w[q], wi = w[q + 4];
            re += dot4(wr, c) + dot4(wi, s);
            im += dot4(wi, c) - dot4(wr, s);
        }
        float g = sqrtf(re * re + im * im);
        if (j < NUSER) { minU = fminf(minU, g); sumU += g; }
        else           { sumT += g; }
    }
    return -2.0f * (minU + 0.1f * sumU) - 0.05f * sumT;
}

// R6: raise TLP 2->4 waves/SIMD. R5's structure (per-wave double-buffered LDS,
// global_load_lds w16, source-side XOR swizzle, per-wave vmcnt) is kept, but:
//  - 32-row tiles (4 KB buffers): 8 KB LDS/wave -> ~34 KB/block -> 4 blocks/CU
//    = 16 waves/CU (was 8). Theory: at 2 waves/SIMD the kernel ran ~50% issue
//    efficiency (4.7 TB/s eff. BW); latency bubbles, not VALU or HBM, bound it.
//  - 2 lanes per row (l and l^32 broadcast-read the same row), beams split 6/6;
//    combine (min,sumU,sumT) with 3 shfl_xor(32). Same FLOPs; halves the
//    per-row table ds_read instruction count (48 vs 96).
//  - finalize fused via last-block done-counter (one fewer graph node).
__global__ __launch_bounds__(256, 4) void mtl_gains_kernel(const float* __restrict__ W,
                                                           const float* __restrict__ table,
                                                           double* __restrict__ acc,
                                                           unsigned* __restrict__ done,
                                                           float* __restrict__ out, int rows) {
    __shared__ float sh[4 * 2 * 1024];      // 32 KB: 4 waves x 2 buffers x 4 KB
    __shared__ float tbs[NBEAM * 2 * NA];   // steering table, 384 floats
    __shared__ float wsum[4];

    const int t = threadIdx.x;
    for (int i = t; i < NBEAM * 2 * NA; i += blockDim.x) tbs[i] = table[i];
    __syncthreads();

    const int wid  = t >> 6;
    const int lane = t & 63;
    float* buf0 = sh + wid * 2048;
    float* buf1 = buf0 + 1024;

    // Source-side XOR swizzle (unchanged formula): staging instr k, lane ->
    // LDS slot p = k*64+lane; row(p)=k*8+(lane>>3), q(p)=lane&7; source quad =
    // row*8 + ((lane&7) ^ (lane>>3)). Keeps LDS dest contiguous for
    // global_load_lds while making the row-major read conflict-minimal.
    const int sq      = (lane & 7) ^ ((lane >> 3) & 7);
    const int src_off = (lane >> 3) * 32 + sq * 4;     // floats within the 1024-float tile

    const int ntiles = rows >> 5;                       // 32-row tiles (62500)
    const int nwaves = gridDim.x * 4;
    const int gw     = blockIdx.x * 4 + wid;
    const int cnt    = ntiles / nwaves;
    const int rem    = ntiles % nwaves;
    const int t0     = gw * cnt + (gw < rem ? gw : rem);
    const int t1     = t0 + cnt + (gw < rem ? 1 : 0);

    // Beam split: lanes 0-31 -> beams 0-5, lanes 32-63 -> beams 6-11, row = lane&31.
    const int h      = lane >> 5;
    const int row    = lane & 31;
    const int jbase  = h * 6;
    const float* tb  = tbs + jbase * 2 * NA;

    float local = 0.f;

    if (t0 < t1) {
        // prologue: stage tile t0 into buf0 (4 x 1 KB)
        {
            const float* src = W + (size_t)t0 * 1024 + src_off;
            #pragma unroll
            for (int k = 0; k < 4; ++k) load_lds16(src + k * 256, buf0 + k * 256);
        }
        #pragma unroll 1
        for (int tt = t0; tt < t1; ++tt) {
            float* cur = ((tt - t0) & 1) ? buf1 : buf0;
            float* nxt = ((tt - t0) & 1) ? buf0 : buf1;
            if (tt + 1 < t1) {
                const float* src = W + (size_t)(tt + 1) * 1024 + src_off;
                #pragma unroll
                for (int k = 0; k < 4; ++k) load_lds16(src + k * 256, nxt + k * 256);
                // 8 staging loads outstanding; wait for tile tt's 4 (oldest),
                // keep tile tt+1's 4 in flight through the compute below.
                asm volatile("s_waitcnt vmcnt(4)" ::: "memory");
            } else {
                asm volatile("s_waitcnt vmcnt(0)" ::: "memory");
            }

            const float* myrow = cur + row * 32;       // lanes l, l^32: same addr (broadcast)
            float4 w[8];
            #pragma unroll
            for (int q = 0; q < 8; ++q) {
                int s = q ^ (row & 7);
                w[q] = *(const float4*)(myrow + s * 4);
            }

            float minU = 3.4e38f, sumU = 0.f, sumT = 0.f;
            #pragma unroll 1
            for (int jj = 0; jj < 6; ++jj) {
                const float4* tc = (const float4*)(tb + jj * 32);
                float re = 0.f, im = 0.f;
                #pragma unroll
                for (int q = 0; q < 4; ++q) {
                    float4 c = tc[q], s = tc[q + 4];
                    float4 wr = w[q], wi = w[q + 4];
                    re += dot4(wr, c) + dot4(wi, s);
                    im += dot4(wi, c) - dot4(wr, s);
                }
                float g = sqrtf(re * re + im * im);
                bool isU = (jbase + jj) < NUSER;
                minU = isU ? fminf(minU, g) : minU;
                sumU += isU ? g : 0.f;
                sumT += isU ? 0.f : g;
            }
            // combine the two half-beam partials across lane pairs (l <-> l^32)
            minU = fminf(minU, __shfl_xor(minU, 32));
            sumU += __shfl_xor(sumU, 32);
            sumT += __shfl_xor(sumT, 32);
            // both lanes of the pair accumulate the full row loss -> weight 0.5
            local += 0.5f * (-2.0f * (minU + 0.1f * sumU) - 0.05f * sumT);
        }
    }

    // generic tail (rows % 32) — zero iterations for rows = 2,000,000
    int tailbase = ntiles << 5;
    if (blockIdx.x == 0) {
        int r = tailbase + t;
        if (r < rows) {
            const float4* wp = (const float4*)(W + (size_t)r * 32);
            float4 w[8];
            #pragma unroll
            for (int i = 0; i < 8; ++i) w[i] = wp[i];
            local += row_loss(w, tbs);
        }
    }

    // wave reduce (64 lanes)
    #pragma unroll
    for (int off = 32; off > 0; off >>= 1) local += __shfl_down(local, off);
    if (lane == 0) wsum[wid] = local;
    __syncthreads();
    if (t == 0) {
        float b = wsum[0] + wsum[1] + wsum[2] + wsum[3];
        atomicAdd(acc, (double)b);
        __threadfence();
        unsigned prev = atomicAdd(done, 1u);
        if (prev == gridDim.x - 1) {
            // all blocks' device-scope adds are ordered before their done-increments;
            // read the final sum with an atomic RMW to bypass any stale cache.
            double total = atomicAdd(acc, 0.0);
            out[0] = (float)(total / (double)rows);
        }
    }
}

extern "C" void kernel_launch(void* const* d_in, const int* in_sizes, int n_in,
                              void* d_out, int out_size, void* d_ws, size_t ws_size,
                              hipStream_t stream) {
    const float* W    = (const float*)d_in[0];
    const float* Hc_r = (const float*)d_in[1];
    const float* Hc_i = (const float*)d_in[2];
    const float* Hs_r = (const float*)d_in[3];
    const float* Hs_i = (const float*)d_in[4];
    float* out = (float*)d_out;

    int rows = in_sizes[0] / (2 * NA);   // 2,000,000
    float*    table = (float*)d_ws;
    double*   acc   = (double*)((char*)d_ws + ACC_OFFSET);
    unsigned* done  = (unsigned*)((char*)d_ws + ACC_OFFSET + 8);

    mtl_angles_kernel<<<1, 64, 0, stream>>>(Hc_r, Hc_i, Hs_r, Hs_i, table, acc, done);

    // 1024 blocks x 4 waves = 4096 waves; ~34 KB LDS/block -> exactly 4 blocks/CU
    // resident = 16 waves/CU (4 waves/SIMD), double R5's latency-hiding TLP.
    mtl_gains_kernel<<<1024, 256, 0, stream>>>(W, table, acc, done, out, rows);
}

// Round 2
// 375.902 us; speedup vs baseline: 1.0864x; 1.0864x over previous
//
#include <hip/hip_runtime.h>
#include <math.h>

#define NA 16
#define NBEAM 12
#define NUSER 8

// ws layout: [0 .. 1535]  : steering table, 12 beams x (16 cos | 16 sin) floats
//            [1536..1543] : double accumulator
#define ACC_OFFSET 1536

__global__ void mtl_angles_kernel(const float* __restrict__ Hc_r, const float* __restrict__ Hc_i,
                                  const float* __restrict__ Hs_r, const float* __restrict__ Hs_i,
                                  float* __restrict__ table, double* __restrict__ acc) {
    int t = threadIdx.x;
    if (t == 0) *acc = 0.0;          // zero the reduction accumulator (ws is poisoned 0xAA)
    if (t >= NBEAM) return;

    const float* re;
    const float* im;
    if (t < NUSER) { re = Hc_r + t * NA;           im = Hc_i + t * NA; }          // Hc[0, t, :]
    else           { re = Hs_r + (t - NUSER) * NA; im = Hs_i + (t - NUSER) * NA; } // Hs[0, t, :]

    const float PI_F   = 3.14159265358979323846f;
    const float TWO_PI = 6.28318530717958647692f;

    float ph[NA];
    #pragma unroll
    for (int n = 0; n < NA; ++n) ph[n] = atan2f(im[n], re[n]);

    // unwrapped[0]=0; unwrapped[n]=cumsum of wrapped diffs. n_c = n - 7.5, sum(n_c^2)=340.
    float unw = 0.f, dotsum = 0.f;
    #pragma unroll
    for (int n = 1; n < NA; ++n) {
        float pd = ph[n] - ph[n - 1];
        float x  = pd + PI_F;
        float m  = fmodf(x, TWO_PI);       // python % has sign of divisor
        if (m < 0.f) m += TWO_PI;
        pd = m - PI_F;
        unw += pd;
        dotsum += unw * ((float)n - 7.5f);
    }
    float slope = dotsum / 340.0f;
    float sin_theta = slope / PI_F;        // slope * WAVELENGTH / (2*pi*D), D=0.5, lambda=1
    sin_theta = fminf(1.0f, fmaxf(-1.0f, sin_theta));
    // angle = -asin(sin_theta); steering uses sin(angle) = -sin_theta
    float st = -sin_theta;

    #pragma unroll
    for (int n = 0; n < NA; ++n) {
        float phase = PI_F * st * (float)n;    // 2*pi*D*st*n/lambda = pi*st*n
        table[t * 2 * NA + n]      = cosf(phase);
        table[t * 2 * NA + NA + n] = sinf(phase);
    }
}

__device__ __forceinline__ float dot4(float4 a, float4 b) {
    return a.x * b.x + a.y * b.y + a.z * b.z + a.w * b.w;
}

// Async global->LDS, 16 B per lane. LDS dest is wave-uniform base + lane*16.
__device__ __forceinline__ void load_lds16(const float* g, float* l) {
    __builtin_amdgcn_global_load_lds(
        (const __attribute__((address_space(1))) void*)g,
        (__attribute__((address_space(3))) void*)l, 16, 0, 0);
}

// One beam's gain: |(Wr+iWi) . (c - i s)| given the beam's 32-float table row.
__device__ __forceinline__ float beam_gain(const float4* w, const float* trow) {
    const float4* tc = (const float4*)trow;
    float re = 0.f, im = 0.f;
    #pragma unroll
    for (int q = 0; q < 4; ++q) {
        float4 c = tc[q], s = tc[q + 4];
        float4 wr = w[q], wi = w[q + 4];
        re += dot4(wr, c) + dot4(wi, s);
        im += dot4(wi, c) - dot4(wr, s);
    }
    return sqrtf(re * re + im * im);
}

// Full-row loss (all 12 beams) — used only by the generic tail path.
__device__ __forceinline__ float row_loss(const float4* w, const float* tbs) {
    float minU = 3.4e38f, sumU = 0.f, sumT = 0.f;
    #pragma unroll 1
    for (int j = 0; j < NBEAM; ++j) {
        float g = beam_gain(w, tbs + j * 32);
        if (j < NUSER) { minU = fminf(minU, g); sumU += g; }
        else           { sumT += g; }
    }
    return -2.0f * (minU + 0.1f * sumU) - 0.05f * sumT;
}

// R7: de-risked 4-blocks/CU version of R6.
//  - R6 post-mortem: gains 57->155us with VGPR squeezed to 64 (launch_bounds
//    (256,4) let the allocator target 8 waves/EU), per-block __threadfence()
//    issuing 1024 agent-scope L2 writebacks mid-stream, and cndmask-chains in
//    the beam split. None of that tested the occupancy theory.
//  - This round: same staging (global_load_lds w16, source XOR swizzle,
//    per-wave vmcnt, 32-row tiles double-buffered = 34 KB/block -> 4 blocks/CU
//    = 16 waves/CU), but: (a) separate finalize kernel again (no fence/done);
//    (b) beam split is 4-user + 2-target per half-wave - compile-time
//    classification, no selects, no divergence; (c) amdgpu_waves_per_eu(4,4)
//    pins the allocator at exactly 4 waves/SIMD (VGPR budget 128, not 64).
__global__ __launch_bounds__(256)
__attribute__((amdgpu_waves_per_eu(4, 4)))
void mtl_gains_kernel(const float* __restrict__ W,
                      const float* __restrict__ table,
                      double* __restrict__ acc, int rows) {
    __shared__ float sh[4 * 2 * 1024];      // 32 KB: 4 waves x 2 buffers x 4 KB
    __shared__ float tbs[NBEAM * 2 * NA];   // steering table, 384 floats
    __shared__ float wsum[4];

    const int t = threadIdx.x;
    for (int i = t; i < NBEAM * 2 * NA; i += blockDim.x) tbs[i] = table[i];
    __syncthreads();

    const int wid  = t >> 6;
    const int lane = t & 63;
    float* buf0 = sh + wid * 2048;
    float* buf1 = buf0 + 1024;

    // Source-side XOR swizzle (verified in R5/R6): staging instr k, lane ->
    // LDS slot p = k*64+lane; row(p)=k*8+(lane>>3), q(p)=lane&7; source quad =
    // row*8 + ((lane&7) ^ (lane>>3)). LDS dest stays contiguous for
    // global_load_lds; row-major b128 reads hit all 32 banks.
    const int sq      = (lane & 7) ^ ((lane >> 3) & 7);
    const int src_off = (lane >> 3) * 32 + sq * 4;     // floats within the 1024-float tile

    const int ntiles = rows >> 5;                       // 32-row tiles (62500)
    const int nwaves = gridDim.x * 4;
    const int gw     = blockIdx.x * 4 + wid;
    const int cnt    = ntiles / nwaves;
    const int rem    = ntiles % nwaves;
    const int t0     = gw * cnt + (gw < rem ? gw : rem);
    const int t1     = t0 + cnt + (gw < rem ? 1 : 0);

    // Pair scheme: lanes l and l^32 both process row = lane&31 (same-address
    // LDS read = broadcast). Beam partition per half h = lane>>5:
    //   user beams   h*4 .. h*4+3   (4 of the 8)
    //   target beams 8+2h, 9+2h     (2 of the 4)
    // -> identical uniform code on both halves, combine via 3 shfl_xor(32).
    const int h      = lane >> 5;
    const int row    = lane & 31;
    const float* tbU = tbs + h * 4 * 32;
    const float* tbT = tbs + (8 + h * 2) * 32;

    float local = 0.f;

    if (t0 < t1) {
        // prologue: stage tile t0 into buf0 (4 x 1 KB)
        {
            const float* src = W + (size_t)t0 * 1024 + src_off;
            #pragma unroll
            for (int k = 0; k < 4; ++k) load_lds16(src + k * 256, buf0 + k * 256);
        }
        #pragma unroll 1
        for (int tt = t0; tt < t1; ++tt) {
            float* cur = ((tt - t0) & 1) ? buf1 : buf0;
            float* nxt = ((tt - t0) & 1) ? buf0 : buf1;
            if (tt + 1 < t1) {
                const float* src = W + (size_t)(tt + 1) * 1024 + src_off;
                #pragma unroll
                for (int k = 0; k < 4; ++k) load_lds16(src + k * 256, nxt + k * 256);
                // 8 staging loads outstanding; wait for tile tt's 4 (oldest),
                // keep tile tt+1's 4 in flight through the compute below.
                asm volatile("s_waitcnt vmcnt(4)" ::: "memory");
            } else {
                asm volatile("s_waitcnt vmcnt(0)" ::: "memory");
            }

            const float* myrow = cur + row * 32;       // lanes l, l^32: same addr (broadcast)
            float4 w[8];
            #pragma unroll
            for (int q = 0; q < 8; ++q) {
                int s = q ^ (row & 7);
                w[q] = *(const float4*)(myrow + s * 4);
            }

            float minU = 3.4e38f, sumU = 0.f, sumT = 0.f;
            #pragma unroll 1
            for (int jj = 0; jj < 4; ++jj) {
                float g = beam_gain(w, tbU + jj * 32);
                minU = fminf(minU, g);
                sumU += g;
            }
            #pragma unroll 1
            for (int jj = 0; jj < 2; ++jj) {
                sumT += beam_gain(w, tbT + jj * 32);
            }
            // combine the two half-beam partials across lane pairs (l <-> l^32)
            minU = fminf(minU, __shfl_xor(minU, 32));
            sumU += __shfl_xor(sumU, 32);
            sumT += __shfl_xor(sumT, 32);
            // both lanes of the pair accumulate the full row loss -> weight 0.5
            local += 0.5f * (-2.0f * (minU + 0.1f * sumU) - 0.05f * sumT);
        }
    }

    // generic tail (rows % 32) — zero iterations for rows = 2,000,000
    int tailbase = ntiles << 5;
    if (blockIdx.x == 0) {
        int r = tailbase + t;
        if (r < rows) {
            const float4* wp = (const float4*)(W + (size_t)r * 32);
            float4 w[8];
            #pragma unroll
            for (int i = 0; i < 8; ++i) w[i] = wp[i];
            local += row_loss(w, tbs);
        }
    }

    // wave reduce (64 lanes)
    #pragma unroll
    for (int off = 32; off > 0; off >>= 1) local += __shfl_down(local, off);
    if (lane == 0) wsum[wid] = local;
    __syncthreads();
    if (t == 0) {
        float b = wsum[0] + wsum[1] + wsum[2] + wsum[3];
        atomicAdd(acc, (double)b);
    }
}

__global__ void mtl_finalize_kernel(const double* __restrict__ acc, float* __restrict__ out, int rows) {
    if (threadIdx.x == 0) out[0] = (float)(*acc / (double)rows);
}

extern "C" void kernel_launch(void* const* d_in, const int* in_sizes, int n_in,
                              void* d_out, int out_size, void* d_ws, size_t ws_size,
                              hipStream_t stream) {
    const float* W    = (const float*)d_in[0];
    const float* Hc_r = (const float*)d_in[1];
    const float* Hc_i = (const float*)d_in[2];
    const float* Hs_r = (const float*)d_in[3];
    const float* Hs_i = (const float*)d_in[4];
    float* out = (float*)d_out;

    int rows = in_sizes[0] / (2 * NA);   // 2,000,000
    float*  table = (float*)d_ws;
    double* acc   = (double*)((char*)d_ws + ACC_OFFSET);

    mtl_angles_kernel<<<1, 64, 0, stream>>>(Hc_r, Hc_i, Hs_r, Hs_i, table, acc);

    // 1024 blocks x 4 waves = 4096 waves; ~34 KB LDS/block -> 4 blocks/CU
    // resident = 16 waves/CU (4 waves/SIMD).
    mtl_gains_kernel<<<1024, 256, 0, stream>>>(W, table, acc, rows);

    mtl_finalize_kernel<<<1, 64, 0, stream>>>(acc, out, rows);
}